// Round 7
// baseline (162.026 us; speedup 1.0000x reference)
//
#include <hip/hip_runtime.h>
#include <math.h>

#define N_ 8192
#define D_ 512
#define NC_ 128
#define T32 32     // 8192/256 row-tiles
#define BK_ 64     // K-step
#define KSTEPS 8   // 512/64

typedef __attribute__((ext_vector_type(8))) short bf16x8;
typedef __attribute__((ext_vector_type(4))) float f32x4;
typedef __attribute__((ext_vector_type(4))) unsigned short us4;

static __device__ __forceinline__ unsigned short f2bf(float f) {
    union { float f; unsigned u; } c; c.f = f;
    unsigned u = c.u;
    u += 0x7fffu + ((u >> 16) & 1u);   // round-to-nearest-even
    return (unsigned short)(u >> 16);
}

// ---------- kernel 1: convert + last-row fp64 dots + histogram (wide) --------
// blocks [0,4096): fp32 -> bf16 convert; [4096,6144): last-row dots (1 wave/row);
// [6144,6176): class histogram slices. Block 0 also zeroes global accumulators.
__global__ __launch_bounds__(256) void k_pre(const float* __restrict__ x,
                                             unsigned short* __restrict__ xb,
                                             const int* __restrict__ tg,
                                             double* __restrict__ sim_last,
                                             int* __restrict__ hist32,
                                             double* __restrict__ gd,
                                             int* __restrict__ gi) {
    const int bid = blockIdx.x;
    const int tid = threadIdx.x;
    if (bid == 0 && tid == 0) {
        atomicExch((unsigned long long*)&gd[0], 0ull);
        atomicExch((unsigned long long*)&gd[1], 0ull);
        atomicExch((unsigned long long*)&gd[2], 0ull);
        atomicExch(&gi[0], 0); atomicExch(&gi[1], 0);
        atomicExch(&gi[2], 0); atomicExch(&gi[3], 0);
    }
    if (bid < 4096) {
        int i = bid * 256 + tid;
        float4 v = reinterpret_cast<const float4*>(x)[i];
        us4 o = { f2bf(v.x), f2bf(v.y), f2bf(v.z), f2bf(v.w) };
        reinterpret_cast<us4*>(xb)[i] = o;
    } else if (bid < 6144) {
        int j    = (bid - 4096) * 4 + (tid >> 6);
        int lane = tid & 63;
        const float* xl = x + (size_t)(N_ - 1) * D_;
        const float* xj = x + (size_t)j * D_;
        double acc = 0.0;
#pragma unroll
        for (int it = 0; it < 8; ++it) {
            int k = it * 64 + lane;
            acc += (double)xl[k] * (double)xj[k];
        }
#pragma unroll
        for (int m = 32; m >= 1; m >>= 1) acc += __shfl_xor(acc, m, 64);
        if (lane == 0) sim_last[j] = acc;
    } else {
        __shared__ int lh[NC_];
        int b = bid - 6144;                 // 0..31
        if (tid < NC_) lh[tid] = 0;
        __syncthreads();
        atomicAdd(&lh[tg[b * 256 + tid]], 1);
        __syncthreads();
        if (tid < NC_) hist32[b * NC_ + tid] = lh[tid];
    }
}

// ---------- kernel 2: 256x256-tile MFMA sim + masked exp partials -----------
// grid = 528 triangular tile-pairs (it<=jt), 512 threads = 8 waves (2x4).
// R3's verified structure with the register-cap bug fixed:
// __launch_bounds__(512, 1) -> VGPR cap 256 (acc[8][4] = 128 f32 fits, no spill).
// Counted-vmcnt 2-deep pipeline (R4-proven TILE macro), LDS = 128 KiB,
// 1 block/CU. Stages 270 MB total (4x less than 128^2 tiling) against the
// ~13.5 TB/s global_load_lds delivery ceiling.
__global__ __launch_bounds__(512, 1) void k_main(const unsigned short* __restrict__ xb,
                                                 const int* __restrict__ tg,
                                                 float* __restrict__ bufP,
                                                 float* __restrict__ bufN) {
    __shared__ alignas(16) unsigned short As0_[2 * 256 * 64];  // 64 KiB
    __shared__ alignas(16) unsigned short Bs0_[2 * 256 * 64];  // 64 KiB

    const int tid  = threadIdx.x;
    const int w    = tid >> 6;        // wave 0..7
    const int lane = tid & 63;
    const int q    = lane >> 4;
    const int l15  = lane & 15;
    const int wrow = w >> 2;          // 0..1 (128-row half)
    const int wcol = w & 3;           // 0..3 (64-col quarter)

    // XCD-chunked bijective swizzle (528 = 8*66)
    const int bswz = (blockIdx.x & 7) * 66 + (blockIdx.x >> 3);

    // triangular decode: bswz -> (it, jt), it<=jt
    int rem = bswz;
    int it = 0;
    while (rem >= (T32 - it)) { rem -= (T32 - it); it++; }
    const int jt = it + rem;
    const int row0 = it * 256;
    const int col0 = jt * 256;

    // stage one K-tile (A 256x64 + B 256x64) into buffer p: 8 gload_lds/lane.
    // XOR-swizzled source: linear LDS slot sl of row r holds granule g=sl^(r&7).
    auto stage_tile = [&](int p, int kt) {
        const int k0 = kt * BK_;
#pragma unroll
        for (int set = 0; set < 4; ++set) {
            int ls = set * 4096 + tid * 8;   // shorts, linear
            int r  = ls >> 6;                // row 0..255
            int sl = (ls >> 3) & 7;
            int g  = sl ^ (r & 7);
            const unsigned short* ga = xb + (size_t)(row0 + r) * D_ + k0 + g * 8;
            const unsigned short* gb = xb + (size_t)(col0 + r) * D_ + k0 + g * 8;
            __builtin_amdgcn_global_load_lds(
                (const __attribute__((address_space(1))) void*)ga,
                (__attribute__((address_space(3))) void*)(As0_ + p * 16384 + set * 4096 + w * 512),
                16, 0, 0);
            __builtin_amdgcn_global_load_lds(
                (const __attribute__((address_space(1))) void*)gb,
                (__attribute__((address_space(3))) void*)(Bs0_ + p * 16384 + set * 4096 + w * 512),
                16, 0, 0);
        }
    };

    f32x4 acc[8][4];
#pragma unroll
    for (int mi = 0; mi < 8; ++mi)
#pragma unroll
        for (int ni = 0; ni < 4; ++ni)
            acc[mi][ni] = (f32x4){0.f, 0.f, 0.f, 0.f};

    // one kc half (K=32) of one tile: 12 ds_read_b128 -> 32 MFMA
    auto compute_kc = [&](int p, int kc) {
        bf16x8 aF[8], bF[4];
#pragma unroll
        for (int mi = 0; mi < 8; ++mi) {
            int rA = wrow * 128 + mi * 16 + l15;
            int sl = (kc * 4 + q) ^ (rA & 7);
            aF[mi] = *reinterpret_cast<const bf16x8*>(As0_ + p * 16384 + rA * 64 + sl * 8);
        }
#pragma unroll
        for (int ni = 0; ni < 4; ++ni) {
            int rB = wcol * 64 + ni * 16 + l15;
            int sl = (kc * 4 + q) ^ (rB & 7);
            bF[ni] = *reinterpret_cast<const bf16x8*>(Bs0_ + p * 16384 + rB * 64 + sl * 8);
        }
        asm volatile("s_waitcnt lgkmcnt(0)" ::: "memory");
        __builtin_amdgcn_sched_barrier(0);   // rule 18: MFMA must not hoist
        __builtin_amdgcn_s_setprio(1);
#pragma unroll
        for (int mi = 0; mi < 8; ++mi)
#pragma unroll
            for (int ni = 0; ni < 4; ++ni)
                acc[mi][ni] = __builtin_amdgcn_mfma_f32_16x16x32_bf16(
                    aF[mi], bF[ni], acc[mi][ni], 0, 0, 0);
        __builtin_amdgcn_s_setprio(0);
    };

#define TILE(P, KS, DOSTAGE, VMN)                                         \
    do {                                                                  \
        asm volatile("s_waitcnt vmcnt(" #VMN ")" ::: "memory");           \
        __builtin_amdgcn_s_barrier();                                     \
        __builtin_amdgcn_sched_barrier(0);                                \
        compute_kc(P, 0);                                                 \
        compute_kc(P, 1);                                                 \
        __builtin_amdgcn_s_barrier();                                     \
        __builtin_amdgcn_sched_barrier(0);                                \
        if (DOSTAGE) stage_tile(P, (KS) + 2);                             \
    } while (0)

    // prologue: two K-tiles in flight (16 gload_lds/lane outstanding)
    stage_tile(0, 0);
    stage_tile(1, 1);

    TILE(0, 0, 1, 8);
    TILE(1, 1, 1, 8);
    TILE(0, 2, 1, 8);
    TILE(1, 3, 1, 8);
    TILE(0, 4, 1, 8);
    TILE(1, 5, 1, 8);
    TILE(0, 6, 0, 8);
    TILE(1, 7, 0, 0);
#undef TILE

    // ---------------- epilogue ----------------
    // target loads only now (K-loop vmcnt counting stayed pure)
    int tC[4];
#pragma unroll
    for (int ni = 0; ni < 4; ++ni)
        tC[ni] = tg[col0 + wcol * 64 + ni * 16 + l15];

    float cps[4], cns[4];
#pragma unroll
    for (int ni = 0; ni < 4; ++ni) { cps[ni] = 0.f; cns[ni] = 0.f; }

    // scr aliases As0_[0] (tile-6 buffer; all its reads completed before the
    // tile-7 leading barrier, which every wave has passed). Last compute reads
    // only the p=1 region (bytes [32768,65536)) -- disjoint from scr (12 KiB).
    float* scr = (float*)As0_;   // rowP[4][256] | rowN[4][256] | colP[2][256] | colN[2][256]

#pragma unroll
    for (int mi = 0; mi < 8; ++mi) {
        int tRv[4];
#pragma unroll
        for (int r = 0; r < 4; ++r)
            tRv[r] = tg[row0 + wrow * 128 + mi * 16 + q * 4 + r];
        float ps_[4] = {0.f, 0.f, 0.f, 0.f};
        float ns_[4] = {0.f, 0.f, 0.f, 0.f};
#pragma unroll
        for (int ni = 0; ni < 4; ++ni)
#pragma unroll
            for (int r = 0; r < 4; ++r) {
                float s = acc[mi][ni][r];
                bool same = (tRv[r] == tC[ni]);
                float e = __expf(same ? 1.0f - s : s);
                float pe = (same && (s < 1.0f)) ? e : 0.0f;
                float ne = same ? 0.0f : e;
                ps_[r] += pe; ns_[r] += ne;
                cps[ni] += pe; cns[ni] += ne;
            }
        // row partials: reduce across the 16 lanes sharing a row
#pragma unroll
        for (int r = 0; r < 4; ++r) {
            float p = ps_[r];
            float n = ns_[r];
#pragma unroll
            for (int m = 1; m < 16; m <<= 1) {
                p += __shfl_xor(p, m, 64);
                n += __shfl_xor(n, m, 64);
            }
            if (l15 == 0) {
                int rloc = wrow * 128 + mi * 16 + q * 4 + r;
                scr[wcol * 256 + rloc]        = p;
                scr[1024 + wcol * 256 + rloc] = n;
            }
        }
    }

    // col partials: reduce across q (lane bits 16,32)
#pragma unroll
    for (int ni = 0; ni < 4; ++ni) {
        float p = cps[ni];
        float n = cns[ni];
        p += __shfl_xor(p, 16, 64); p += __shfl_xor(p, 32, 64);
        n += __shfl_xor(n, 16, 64); n += __shfl_xor(n, 32, 64);
        if (q == 0) {
            int cloc = wcol * 64 + ni * 16 + l15;
            scr[2048 + wrow * 256 + cloc] = p;
            scr[2560 + wrow * 256 + cloc] = n;
        }
    }
    __syncthreads();

    if (tid < 256) {
        int r = tid;
        size_t off = ((size_t)it * T32 + jt) * 256 + r;
        bufP[off] = scr[r] + scr[256 + r] + scr[512 + r] + scr[768 + r];
        bufN[off] = scr[1024 + r] + scr[1280 + r] + scr[1536 + r] + scr[1792 + r];
    } else if (jt != it) {
        int c = tid - 256;
        size_t off = ((size_t)jt * T32 + it) * 256 + c;
        bufP[off] = scr[2048 + c] + scr[2304 + c];
        bufN[off] = scr[2560 + c] + scr[2816 + c];
    }
}

// ---------- kernel 3: reduce + finalize (64 blocks, atomic-chained) ----------
// Block t handles rows [t*128,(t+1)*128): psum/nsum over 32 col-tiles,
// per-row log+skip, last-row stats from sim_last; global fp64/int atomics;
// the block completing the 64th counter-add finalizes out[].
__global__ __launch_bounds__(256) void k_post(const float* __restrict__ bufP,
                                              const float* __restrict__ bufN,
                                              const int* __restrict__ tg,
                                              const int* __restrict__ hist32,
                                              const double* __restrict__ sim_last,
                                              double* __restrict__ gd,
                                              int* __restrict__ gi,
                                              float* __restrict__ out) {
    __shared__ int lh[NC_];
    __shared__ float sv[256];
    __shared__ double Rd[256], Pd[256], Nd[256];
    __shared__ int Ri[256], Pc[256], Nc[256];
    const int t   = blockIdx.x;       // 0..63
    const int tid = threadIdx.x;

    if (tid < NC_) {
        int a = 0;
#pragma unroll
        for (int b = 0; b < 32; ++b) a += hist32[b * NC_ + tid];
        lh[tid] = a;
    }

    const int half = tid >> 7;        // 0: psum, 1: nsum
    const int r    = tid & 127;
    const int rt   = t >> 1;                    // 256-row tile
    const int r256 = (t & 1) * 128 + r;         // row within tile
    const float* buf  = half ? bufN : bufP;
    const float* base = buf + (size_t)rt * T32 * 256 + r256;
    float s = 0.f;
#pragma unroll
    for (int o = 0; o < T32; ++o) s += base[o * 256];
    sv[tid] = s;
    __syncthreads();

    double rd = 0.0, pd = 0.0, nd = 0.0;
    int ri = 0, pc = 0, nc = 0;
    if (tid < 128) {
        int row = t * 128 + tid;
        bool ok = lh[tg[row]] < N_;
        rd = ok ? (double)(logf(sv[tid]) + logf(sv[128 + tid])) : 0.0;
        ri = ok ? 0 : 1;
        double sl = sim_last[row];
        int tlast = tg[N_ - 1];
        if (tg[row] == tlast) { if (sl < 1.0) { pd = sl; pc = 1; } }
        else                  { nd = sl; nc = 1; }
    }

    Rd[tid] = rd; Ri[tid] = ri;
    Pd[tid] = pd; Pc[tid] = pc;
    Nd[tid] = nd; Nc[tid] = nc;
    __syncthreads();
    for (int st = 128; st >= 1; st >>= 1) {
        if (tid < st) {
            Rd[tid] += Rd[tid + st]; Pd[tid] += Pd[tid + st]; Nd[tid] += Nd[tid + st];
            Ri[tid] += Ri[tid + st]; Pc[tid] += Pc[tid + st]; Nc[tid] += Nc[tid + st];
        }
        __syncthreads();
    }

    if (tid == 0) {
        atomicAdd(&gd[0], Rd[0]);
        atomicAdd(&gd[1], Pd[0]);
        atomicAdd(&gd[2], Nd[0]);
        atomicAdd(&gi[0], Ri[0]);
        atomicAdd(&gi[1], Pc[0]);
        atomicAdd(&gi[2], Nc[0]);
        __threadfence();
        int old = atomicAdd(&gi[3], 1);
        if (old == 63) {
            double A = atomicAdd(&gd[0], 0.0);
            double B = atomicAdd(&gd[1], 0.0);
            double C = atomicAdd(&gd[2], 0.0);
            int U = atomicAdd(&gi[0], 0);
            int V = atomicAdd(&gi[1], 0);
            int Y = atomicAdd(&gi[2], 0);
            out[0] = (float)(A / (double)N_);
            out[1] = (float)U / (float)N_;
            out[2] = (float)(B / (double)V);
            out[3] = (float)(C / (double)Y);
        }
    }
}

extern "C" void kernel_launch(void* const* d_in, const int* in_sizes, int n_in,
                              void* d_out, int out_size, void* d_ws, size_t ws_size,
                              hipStream_t stream) {
    const float* x  = (const float*)d_in[0];
    const int*   tg = (const int*)d_in[1];
    char* ws = (char*)d_ws;

    unsigned short* xb = (unsigned short*)ws;                 // 8 MB
    const size_t XB = (size_t)N_ * D_ * 2;                    // 8388608
    float*  bufP = (float*)(ws + XB);                         // 32*32*256*4 = 1 MB
    float*  bufN = (float*)(ws + XB + (1u << 20));            // 1 MB
    double* sim_last = (double*)(ws + XB + (2u << 20));       // 64 KB
    int*    hist32   = (int*)(ws + XB + (2u << 20) + 65536);  // 16 KB
    double* gd   = (double*)(ws + XB + (2u << 20) + 65536 + 16384);    // 3 doubles
    int*    gi   = (int*)(ws + XB + (2u << 20) + 65536 + 16384 + 64);  // 4 ints

    const int nblk_tri = T32 * (T32 + 1) / 2;                 // 528

    hipLaunchKernelGGL(k_pre, dim3(4096 + 2048 + 32), dim3(256), 0, stream,
                       x, xb, tg, sim_last, hist32, gd, gi);
    hipLaunchKernelGGL(k_main, dim3(nblk_tri), dim3(512), 0, stream, xb, tg, bufP, bufN);
    hipLaunchKernelGGL(k_post, dim3(64), dim3(256), 0, stream,
                       bufP, bufN, tg, hist32, sim_last, gd, gi, (float*)d_out);
}

// Round 8
// 149.443 us; speedup vs baseline: 1.0842x; 1.0842x over previous
//
#include <hip/hip_runtime.h>
#include <math.h>

#define N_ 8192
#define D_ 512
#define NC_ 128
#define T_ 64      // 8192/128 row-tiles
#define BK_ 64     // K-step
#define KSTEPS 8   // 512/64

typedef __attribute__((ext_vector_type(8))) short bf16x8;
typedef __attribute__((ext_vector_type(4))) float f32x4;
typedef __attribute__((ext_vector_type(4))) unsigned short us4;

static __device__ __forceinline__ unsigned short f2bf(float f) {
    union { float f; unsigned u; } c; c.f = f;
    unsigned u = c.u;
    u += 0x7fffu + ((u >> 16) & 1u);   // round-to-nearest-even
    return (unsigned short)(u >> 16);
}

// ---------- kernel 1: convert + last-row fp64 dots + histogram (wide) --------
// blocks [0,4096): fp32 -> bf16 convert; [4096,6144): last-row dots (1 wave/row);
// [6144,6176): class histogram slices. Block 0 also zeroes global accumulators.
__global__ __launch_bounds__(256) void k_pre(const float* __restrict__ x,
                                             unsigned short* __restrict__ xb,
                                             const int* __restrict__ tg,
                                             double* __restrict__ sim_last,
                                             int* __restrict__ hist32,
                                             double* __restrict__ gd,
                                             int* __restrict__ gi) {
    const int bid = blockIdx.x;
    const int tid = threadIdx.x;
    if (bid == 0 && tid == 0) {
        atomicExch((unsigned long long*)&gd[0], 0ull);
        atomicExch((unsigned long long*)&gd[1], 0ull);
        atomicExch((unsigned long long*)&gd[2], 0ull);
        atomicExch(&gi[0], 0); atomicExch(&gi[1], 0);
        atomicExch(&gi[2], 0); atomicExch(&gi[3], 0);
    }
    if (bid < 4096) {
        int i = bid * 256 + tid;
        float4 v = reinterpret_cast<const float4*>(x)[i];
        us4 o = { f2bf(v.x), f2bf(v.y), f2bf(v.z), f2bf(v.w) };
        reinterpret_cast<us4*>(xb)[i] = o;
    } else if (bid < 6144) {
        int j    = (bid - 4096) * 4 + (tid >> 6);
        int lane = tid & 63;
        const float* xl = x + (size_t)(N_ - 1) * D_;
        const float* xj = x + (size_t)j * D_;
        double acc = 0.0;
#pragma unroll
        for (int it = 0; it < 8; ++it) {
            int k = it * 64 + lane;
            acc += (double)xl[k] * (double)xj[k];
        }
#pragma unroll
        for (int m = 32; m >= 1; m >>= 1) acc += __shfl_xor(acc, m, 64);
        if (lane == 0) sim_last[j] = acc;
    } else {
        __shared__ int lh[NC_];
        int b = bid - 6144;                 // 0..31
        if (tid < NC_) lh[tid] = 0;
        __syncthreads();
        atomicAdd(&lh[tg[b * 256 + tid]], 1);
        __syncthreads();
        if (tid < NC_) hist32[b * NC_ + tid] = lh[tid];
    }
}

// ---------- kernel 2: symmetric fused bf16 MFMA sim + masked exp partials ----
// R4's verified kernel, verbatim: grid = 2080 triangular tile-pairs (it<=jt),
// 128x128 tile, 256 threads (2x2 waves), BK=64, 64 KiB LDS -> 2 blocks/CU.
// Counted-vmcnt 2-deep pipeline: s_waitcnt vmcnt(8) per step (waits loads
// issued two steps ago), raw s_barrier, restage into freed buffer after the
// trailing barrier. vmcnt drains to 0 only at the last tile.
__global__ __launch_bounds__(256, 2) void k_main(const unsigned short* __restrict__ xb,
                                                 const int* __restrict__ tg,
                                                 float* __restrict__ bufP,
                                                 float* __restrict__ bufN) {
    __shared__ alignas(16) unsigned short As[2][128 * 64];   // 32 KiB
    __shared__ alignas(16) unsigned short Bs[2][128 * 64];   // 32 KiB

    const int tid  = threadIdx.x;
    const int w    = tid >> 6;
    const int lane = tid & 63;
    const int q    = lane >> 4;
    const int l15  = lane & 15;
    const int wrow = w >> 1;      // 0..1
    const int wcol = w & 1;       // 0..1

    // XCD-chunked bijective swizzle (2080 = 8*260)
    const int bswz = (blockIdx.x & 7) * 260 + (blockIdx.x >> 3);

    // triangular decode: bswz -> (it, jt), it<=jt
    int rem = bswz;
    int it = 0;
    while (rem >= (T_ - it)) { rem -= (T_ - it); it++; }
    const int jt = it + rem;
    const int row0 = it * 128;
    const int col0 = jt * 128;

    // stage A(128x64) + B(128x64) of K-tile kt into buffer p: 8 gload_lds/lane.
    // XOR-swizzled source: LDS slot s of row r holds kgroup g = s ^ (r&7).
    auto stage_tile = [&](int p, int kt) {
        const int k0 = kt * BK_;
#pragma unroll
        for (int itr = 0; itr < 4; ++itr) {
            int gs = (itr * 4 + w) * 64 + lane;   // 16B-chunk id 0..1023
            int r  = gs >> 3;
            int s  = gs & 7;
            int g  = s ^ (r & 7);
            const unsigned short* ga = xb + (size_t)(row0 + r) * D_ + k0 + g * 8;
            const unsigned short* gb = xb + (size_t)(col0 + r) * D_ + k0 + g * 8;
            __builtin_amdgcn_global_load_lds(
                (const __attribute__((address_space(1))) void*)ga,
                (__attribute__((address_space(3))) void*)(&As[p][0] + (itr * 4 + w) * 512),
                16, 0, 0);
            __builtin_amdgcn_global_load_lds(
                (const __attribute__((address_space(1))) void*)gb,
                (__attribute__((address_space(3))) void*)(&Bs[p][0] + (itr * 4 + w) * 512),
                16, 0, 0);
        }
    };

    f32x4 acc[4][4];
#pragma unroll
    for (int mi = 0; mi < 4; ++mi)
#pragma unroll
        for (int ni = 0; ni < 4; ++ni)
            acc[mi][ni] = (f32x4){0.f, 0.f, 0.f, 0.f};

    auto compute_tile = [&](int p) {
#pragma unroll
        for (int kc = 0; kc < 2; ++kc) {
            bf16x8 aF[4], bF[4];
#pragma unroll
            for (int mi = 0; mi < 4; ++mi) {
                int rA = wrow * 64 + mi * 16 + l15;
                int sl = (kc * 4 + q) ^ (rA & 7);
                aF[mi] = *reinterpret_cast<const bf16x8*>(&As[p][0] + rA * 64 + sl * 8);
            }
#pragma unroll
            for (int ni = 0; ni < 4; ++ni) {
                int rB = wcol * 64 + ni * 16 + l15;
                int sl = (kc * 4 + q) ^ (rB & 7);
                bF[ni] = *reinterpret_cast<const bf16x8*>(&Bs[p][0] + rB * 64 + sl * 8);
            }
            asm volatile("s_waitcnt lgkmcnt(0)" ::: "memory");
            __builtin_amdgcn_sched_barrier(0);   // rule 18: MFMA must not hoist
            __builtin_amdgcn_s_setprio(1);
#pragma unroll
            for (int mi = 0; mi < 4; ++mi)
#pragma unroll
                for (int ni = 0; ni < 4; ++ni)
                    acc[mi][ni] = __builtin_amdgcn_mfma_f32_16x16x32_bf16(
                        aF[mi], bF[ni], acc[mi][ni], 0, 0, 0);
            __builtin_amdgcn_s_setprio(0);
        }
    };

#define TILE(P, KS, DOSTAGE, VMN)                                         \
    do {                                                                  \
        asm volatile("s_waitcnt vmcnt(" #VMN ")" ::: "memory");           \
        __builtin_amdgcn_s_barrier();                                     \
        __builtin_amdgcn_sched_barrier(0);                                \
        compute_tile(P);                                                  \
        __builtin_amdgcn_s_barrier();                                     \
        __builtin_amdgcn_sched_barrier(0);                                \
        if (DOSTAGE) stage_tile(P, (KS) + 2);                             \
    } while (0)

    // prologue: two K-tiles in flight (16 gload_lds/lane outstanding)
    stage_tile(0, 0);
    stage_tile(1, 1);

    TILE(0, 0, 1, 8);
    TILE(1, 1, 1, 8);
    TILE(0, 2, 1, 8);
    TILE(1, 3, 1, 8);
    TILE(0, 4, 1, 8);
    TILE(1, 5, 1, 8);
    TILE(0, 6, 0, 8);
    TILE(1, 7, 0, 0);
#undef TILE

    // ---------------- epilogue ----------------
    // target loads only now (K-loop vmcnt counting stayed pure)
    int tC[4];
#pragma unroll
    for (int ni = 0; ni < 4; ++ni)
        tC[ni] = tg[col0 + wcol * 64 + ni * 16 + l15];

    float ps[4][4], ns[4][4];
    float cps[4], cns[4];
    int tR[4][4];
#pragma unroll
    for (int mi = 0; mi < 4; ++mi)
#pragma unroll
        for (int r = 0; r < 4; ++r) {
            ps[mi][r] = 0.f; ns[mi][r] = 0.f;
            tR[mi][r] = tg[row0 + wrow * 64 + mi * 16 + q * 4 + r];
        }
#pragma unroll
    for (int ni = 0; ni < 4; ++ni) { cps[ni] = 0.f; cns[ni] = 0.f; }

#pragma unroll
    for (int mi = 0; mi < 4; ++mi)
#pragma unroll
        for (int ni = 0; ni < 4; ++ni)
#pragma unroll
            for (int r = 0; r < 4; ++r) {
                float s = acc[mi][ni][r];
                bool same = (tR[mi][r] == tC[ni]);
                float e = __expf(same ? 1.0f - s : s);
                float pe = (same && (s < 1.0f)) ? e : 0.0f;
                float ne = same ? 0.0f : e;
                ps[mi][r] += pe; ns[mi][r] += ne;
                cps[ni]   += pe; cns[ni]   += ne;
            }

    // combine wave halves through LDS scratch = As[0] (last compute used buf 1;
    // As[0] was last read at tile 6, before tile 7's leading barrier)
    float* scr = (float*)As;         // [0:256)=rowP, [256:512)=rowN,
                                     // [512:768)=colP, [768:1024)=colN
#pragma unroll
    for (int mi = 0; mi < 4; ++mi)
#pragma unroll
        for (int r = 0; r < 4; ++r) {
            float p = ps[mi][r];
            float n = ns[mi][r];
#pragma unroll
            for (int m = 1; m < 16; m <<= 1) {
                p += __shfl_xor(p, m, 64);
                n += __shfl_xor(n, m, 64);
            }
            if (l15 == 0) {
                int rloc = wrow * 64 + mi * 16 + q * 4 + r;
                scr[wcol * 128 + rloc]       = p;
                scr[256 + wcol * 128 + rloc] = n;
            }
        }

#pragma unroll
    for (int ni = 0; ni < 4; ++ni) {
        float p = cps[ni];
        float n = cns[ni];
        p += __shfl_xor(p, 16, 64); p += __shfl_xor(p, 32, 64);
        n += __shfl_xor(n, 16, 64); n += __shfl_xor(n, 32, 64);
        if (q == 0) {
            int cloc = wcol * 64 + ni * 16 + l15;
            scr[512 + wrow * 128 + cloc] = p;
            scr[768 + wrow * 128 + cloc] = n;
        }
    }
    __syncthreads();

    if (tid < 128) {
        int r = tid;
        size_t off = ((size_t)it * T_ + jt) * 128 + r;
        bufP[off] = scr[r]       + scr[128 + r];
        bufN[off] = scr[256 + r] + scr[384 + r];
    } else if (jt != it) {
        int c = tid - 128;
        size_t off = ((size_t)jt * T_ + it) * 128 + c;
        bufP[off] = scr[512 + c] + scr[640 + c];
        bufN[off] = scr[768 + c] + scr[896 + c];
    }
}

// ---------- kernel 3: reduce + finalize (64 blocks, atomic-chained) ----------
__global__ __launch_bounds__(256) void k_post(const float* __restrict__ bufP,
                                              const float* __restrict__ bufN,
                                              const int* __restrict__ tg,
                                              const int* __restrict__ hist32,
                                              const double* __restrict__ sim_last,
                                              double* __restrict__ gd,
                                              int* __restrict__ gi,
                                              float* __restrict__ out) {
    __shared__ int lh[NC_];
    __shared__ float sv[256];
    __shared__ double Rd[256], Pd[256], Nd[256];
    __shared__ int Ri[256], Pc[256], Nc[256];
    const int t   = blockIdx.x;       // 0..63
    const int tid = threadIdx.x;

    if (tid < NC_) {
        int a = 0;
#pragma unroll
        for (int b = 0; b < 32; ++b) a += hist32[b * NC_ + tid];
        lh[tid] = a;
    }

    const int half = tid >> 7;        // 0: psum, 1: nsum
    const int r    = tid & 127;
    const float* buf  = half ? bufN : bufP;
    const float* base = buf + (size_t)t * T_ * 128 + r;
    float s = 0.f;
#pragma unroll
    for (int o = 0; o < T_; ++o) s += base[o * 128];
    sv[tid] = s;
    __syncthreads();

    double rd = 0.0, pd = 0.0, nd = 0.0;
    int ri = 0, pc = 0, nc = 0;
    if (tid < 128) {
        int row = t * 128 + tid;
        bool ok = lh[tg[row]] < N_;
        rd = ok ? (double)(logf(sv[tid]) + logf(sv[128 + tid])) : 0.0;
        ri = ok ? 0 : 1;
        double sl = sim_last[row];
        int tlast = tg[N_ - 1];
        if (tg[row] == tlast) { if (sl < 1.0) { pd = sl; pc = 1; } }
        else                  { nd = sl; nc = 1; }
    }

    Rd[tid] = rd; Ri[tid] = ri;
    Pd[tid] = pd; Pc[tid] = pc;
    Nd[tid] = nd; Nc[tid] = nc;
    __syncthreads();
    for (int st = 128; st >= 1; st >>= 1) {
        if (tid < st) {
            Rd[tid] += Rd[tid + st]; Pd[tid] += Pd[tid + st]; Nd[tid] += Nd[tid + st];
            Ri[tid] += Ri[tid + st]; Pc[tid] += Pc[tid + st]; Nc[tid] += Nc[tid + st];
        }
        __syncthreads();
    }

    if (tid == 0) {
        atomicAdd(&gd[0], Rd[0]);
        atomicAdd(&gd[1], Pd[0]);
        atomicAdd(&gd[2], Nd[0]);
        atomicAdd(&gi[0], Ri[0]);
        atomicAdd(&gi[1], Pc[0]);
        atomicAdd(&gi[2], Nc[0]);
        __threadfence();
        int old = atomicAdd(&gi[3], 1);
        if (old == 63) {
            double A = atomicAdd(&gd[0], 0.0);
            double B = atomicAdd(&gd[1], 0.0);
            double C = atomicAdd(&gd[2], 0.0);
            int U = atomicAdd(&gi[0], 0);
            int V = atomicAdd(&gi[1], 0);
            int Y = atomicAdd(&gi[2], 0);
            out[0] = (float)(A / (double)N_);
            out[1] = (float)U / (float)N_;
            out[2] = (float)(B / (double)V);
            out[3] = (float)(C / (double)Y);
        }
    }
}

extern "C" void kernel_launch(void* const* d_in, const int* in_sizes, int n_in,
                              void* d_out, int out_size, void* d_ws, size_t ws_size,
                              hipStream_t stream) {
    const float* x  = (const float*)d_in[0];
    const int*   tg = (const int*)d_in[1];
    char* ws = (char*)d_ws;

    unsigned short* xb = (unsigned short*)ws;                 // 8 MB
    const size_t XB = (size_t)N_ * D_ * 2;                    // 8388608
    float*  bufP = (float*)(ws + XB);                         // 2 MB
    float*  bufN = (float*)(ws + XB + 2097152);               // 2 MB
    double* sim_last = (double*)(ws + XB + 4194304);          // 64 KB
    int*    hist32   = (int*)(ws + XB + 4194304 + 65536);     // 16 KB
    double* gd   = (double*)(ws + XB + 4194304 + 65536 + 16384);      // 3 doubles
    int*    gi   = (int*)(ws + XB + 4194304 + 65536 + 16384 + 64);    // 4 ints

    const int nblk_tri = T_ * (T_ + 1) / 2;                   // 2080

    hipLaunchKernelGGL(k_pre, dim3(4096 + 2048 + 32), dim3(256), 0, stream,
                       x, xb, tg, sim_last, hist32, gd, gi);
    hipLaunchKernelGGL(k_main, dim3(nblk_tri), dim3(256), 0, stream, xb, tg, bufP, bufN);
    hipLaunchKernelGGL(k_post, dim3(64), dim3(256), 0, stream,
                       bufP, bufN, tg, hist32, sim_last, gd, gi, (float*)d_out);
}